// Round 5
// baseline (851.041 us; speedup 1.0000x reference)
//
#include <hip/hip_runtime.h>
#include <math.h>

#define Bdim 8
#define Tdim 12
#define BT   96
#define Ndim 1024
#define Cdim 64
#define Ddim 10
#define Jdim 6144      // BT*C
#define IOdim 4096     // C*C

typedef __attribute__((ext_vector_type(4))) float f32x4;
typedef __attribute__((ext_vector_type(8))) short bf16x8;
typedef __attribute__((ext_vector_type(4))) short bf16x4;

__device__ inline short f2bf(float f) {
    union { float f; unsigned u; } v; v.f = f;
    return (short)((v.u + 0x8000u) >> 16);
}
__device__ inline float bf2f(short s) {
    union { float f; unsigned u; } v; v.u = ((unsigned)(unsigned short)s) << 16;
    return v.f;
}
__device__ inline void load_lds16(const void* g, void* l) {
    __builtin_amdgcn_global_load_lds(
        (const __attribute__((address_space(1))) unsigned int*)g,
        (__attribute__((address_space(3))) unsigned int*)l, 16, 0, 0);
}

// ---------------------------------------------------------------- supports (bf16)
__global__ __launch_bounds__(256) void k_supports(
    const float* __restrict__ e1, const float* __restrict__ e2,
    short* __restrict__ Sbf)
{
    int idx = blockIdx.x * 256 + threadIdx.x;
    int i = idx >> 10, j = idx & 1023;
    float s = 0.f;
#pragma unroll
    for (int d = 0; d < Ddim; ++d)
        s += e1[i * Ddim + d] * e2[j * Ddim + d]
           - e2[i * Ddim + d] * e1[j * Ddim + d];
    float v = fmaxf(tanhf(s), 0.f);
    if (i == j) v += 1.f;
    Sbf[idx] = f2bf(v);
}

// ---------------------------------------------------------------- row softmax (bf16 out)
__global__ __launch_bounds__(256) void k_softmax_rows(
    const float* __restrict__ In, short* __restrict__ Out)
{
    int row = blockIdx.x;
    const float* r = In + (size_t)row * Ndim;
    short* o = Out + (size_t)row * Ndim;
    __shared__ float red[256];
    int tid = threadIdx.x;
    float vals[4];
    float lmax = -INFINITY;
#pragma unroll
    for (int i = 0; i < 4; ++i) { vals[i] = r[tid + 256 * i]; lmax = fmaxf(lmax, vals[i]); }
    red[tid] = lmax; __syncthreads();
    for (int s = 128; s > 0; s >>= 1) {
        if (tid < s) red[tid] = fmaxf(red[tid], red[tid + s]);
        __syncthreads();
    }
    float m = red[0]; __syncthreads();
    float lsum = 0.f;
#pragma unroll
    for (int i = 0; i < 4; ++i) { vals[i] = expf(vals[i] - m); lsum += vals[i]; }
    red[tid] = lsum; __syncthreads();
    for (int s = 128; s > 0; s >>= 1) {
        if (tid < s) red[tid] += red[tid + s];
        __syncthreads();
    }
    float inv = 1.0f / red[0];
#pragma unroll
    for (int i = 0; i < 4; ++i) o[tid + 256 * i] = f2bf(vals[i] * inv);
}

// ---------------------------------------------------------------- x -> xbf + xT bf16
__global__ __launch_bounds__(256) void k_cvt_x(
    const float* __restrict__ x, short* __restrict__ xbf, short* __restrict__ xT)
{
    __shared__ float Lt[64][65];
    int bt = blockIdx.y, n0 = blockIdx.x * 64;
    const float* src = x + (size_t)bt * 65536 + (size_t)n0 * 64;
    int tid = threadIdx.x;
#pragma unroll
    for (int p = 0; p < 4; ++p) {
        int idx = p * 256 + tid;
        int r = idx >> 4, c4 = idx & 15;
        float4 v = *(const float4*)&src[r * 64 + c4 * 4];
        short4 s4 = make_short4(f2bf(v.x), f2bf(v.y), f2bf(v.z), f2bf(v.w));
        *(short4*)&xbf[(size_t)bt * 65536 + (size_t)(n0 + r) * 64 + c4 * 4] = s4;
        Lt[r][c4 * 4 + 0] = v.x; Lt[r][c4 * 4 + 1] = v.y;
        Lt[r][c4 * 4 + 2] = v.z; Lt[r][c4 * 4 + 3] = v.w;
    }
    __syncthreads();
#pragma unroll
    for (int p = 0; p < 4; ++p) {
        int idx = p * 256 + tid;
        int c = idx >> 4, k4 = idx & 15;
        short4 s4 = make_short4(f2bf(Lt[k4 * 4 + 0][c]), f2bf(Lt[k4 * 4 + 1][c]),
                                f2bf(Lt[k4 * 4 + 2][c]), f2bf(Lt[k4 * 4 + 3][c]));
        *(short4*)&xT[(size_t)bt * 65536 + (size_t)c * 1024 + n0 + k4 * 4] = s4;
    }
}

// ---------------------------------------------------------------- wpool -> wpT bf16 (4096x1024)
__global__ __launch_bounds__(256) void k_cvt_wp(
    const float* __restrict__ wp, short* __restrict__ wpT)
{
    __shared__ float Lt[64][65];
    int k0 = blockIdx.y * 64, j0 = blockIdx.x * 64;
    int tid = threadIdx.x;
#pragma unroll
    for (int p = 0; p < 4; ++p) {
        int idx = p * 256 + tid;
        int r = idx >> 4, c4 = idx & 15;
        float4 v = *(const float4*)&wp[(size_t)(k0 + r) * IOdim + j0 + c4 * 4];
        Lt[r][c4 * 4 + 0] = v.x; Lt[r][c4 * 4 + 1] = v.y;
        Lt[r][c4 * 4 + 2] = v.z; Lt[r][c4 * 4 + 3] = v.w;
    }
    __syncthreads();
#pragma unroll
    for (int p = 0; p < 4; ++p) {
        int idx = p * 256 + tid;
        int c = idx >> 4, k4 = idx & 15;
        short4 s4 = make_short4(f2bf(Lt[k4 * 4 + 0][c]), f2bf(Lt[k4 * 4 + 1][c]),
                                f2bf(Lt[k4 * 4 + 2][c]), f2bf(Lt[k4 * 4 + 3][c]));
        *(short4*)&wpT[(size_t)(j0 + c) * 1024 + k0 + k4 * 4] = s4;
    }
}

// ---------------------------------------------------------------- m97-style bf16 GEMM, C = A @ B^T
template<int MODE>
__global__ __launch_bounds__(256) void k_gemm_bt(
    const short* __restrict__ A, const short* __restrict__ Bm,
    float* __restrict__ Cf, short* __restrict__ Cb,
    const float* __restrict__ gamma_p)
{
    __shared__ short At[128 * 64];
    __shared__ short Bt[128 * 64];
    const int tid = threadIdx.x;
    const int w = tid >> 6, l = tid & 63;
    const int l15 = l & 15, q = l >> 4;
    const int n0 = blockIdx.x * 128, j0 = blockIdx.y * 128;
    const int wr = (w & 1) * 64, wc = (w >> 1) * 64;
    const int lrow = l >> 3, lc8 = l & 7;

    f32x4 acc[4][4];
#pragma unroll
    for (int i = 0; i < 4; ++i)
#pragma unroll
        for (int j = 0; j < 4; ++j) acc[i][j] = (f32x4)0.f;

    for (int k0 = 0; k0 < 1024; k0 += 64) {
        __syncthreads();
#pragma unroll
        for (int p = 0; p < 4; ++p) {
            int r = p * 32 + w * 8 + lrow;
            int sc = lc8 ^ (r & 7);
            load_lds16(A + (size_t)(n0 + r) * 1024 + k0 + sc * 8,
                       &At[(p * 32 + w * 8) * 64]);
            load_lds16(Bm + (size_t)(j0 + r) * 1024 + k0 + sc * 8,
                       &Bt[(p * 32 + w * 8) * 64]);
        }
        __syncthreads();
#pragma unroll
        for (int ks = 0; ks < 2; ++ks) {
            bf16x8 af[4], bf[4];
#pragma unroll
            for (int rt = 0; rt < 4; ++rt) {
                int row = wr + rt * 16 + l15;
                int pos = (ks * 4 + q) ^ (row & 7);
                af[rt] = *(const bf16x8*)&At[row * 64 + pos * 8];
            }
#pragma unroll
            for (int ct = 0; ct < 4; ++ct) {
                int row = wc + ct * 16 + l15;
                int pos = (ks * 4 + q) ^ (row & 7);
                bf[ct] = *(const bf16x8*)&Bt[row * 64 + pos * 8];
            }
#pragma unroll
            for (int rt = 0; rt < 4; ++rt)
#pragma unroll
                for (int ct = 0; ct < 4; ++ct)
                    acc[rt][ct] = __builtin_amdgcn_mfma_f32_16x16x32_bf16(
                        af[rt], bf[ct], acc[rt][ct], 0, 0, 0);
        }
    }

    float gmm = (MODE == 0) ? gamma_p[0] : 0.f;
#pragma unroll
    for (int rt = 0; rt < 4; ++rt) {
        int nr = n0 + wr + rt * 16 + q * 4;
#pragma unroll
        for (int ct = 0; ct < 4; ++ct) {
            int j = j0 + wc + ct * 16 + l15;
#pragma unroll
            for (int r = 0; r < 4; ++r) {
                float v = acc[rt][ct][r];
                int n = nr + r;
                if (MODE == 1) {
                    Cb[(size_t)n * IOdim + j] = f2bf(v);
                } else if (n < 1024) {
                    int bt = j >> 6, c = j & 63;
                    Cf[(size_t)bt * 65536 + (size_t)n * 64 + c] = gmm * fmaxf(v, 0.f);
                } else {
                    Cb[(size_t)(n - 1024) * Jdim + j] = f2bf(v);
                }
            }
        }
    }
}

// ---------------------------------------------------------------- spatial attention v4
// Barrier-free, LDS-free. m processed in 32-chunks as TWO 16-row score MFMAs
// whose A-operand rows are permuted: C/D row rho <-> m = m0+(rho>>2)*8+(rho&3)+4*tau.
// After the per-lane softmax over t, lane (l15,q) holds P at (n=l15, m=q*8+0..7)
// across the two tiles == exactly the 16x16x32 A-operand layout for PV.
// Only the session-proven mfma_f32_16x16x32_bf16 builtin is used.
__global__ __launch_bounds__(256, 2) void k_sa4(
    const short* __restrict__ xbf, const short* __restrict__ xT,
    float* __restrict__ Out, const float* __restrict__ beta_p)
{
    int b  = blockIdx.x;           // b fastest -> same-XCD blocks share b
    int n0 = blockIdx.y * 16;
    int tid = threadIdx.x;
    int w = tid >> 6, l = tid & 63;
    int l15 = l & 15, q = l >> 4;

    const short* Xb = xbf + (size_t)b * Tdim * 65536;
    const short* XT = xT  + (size_t)b * Tdim * 65536;

    // Q B-frags, register-cached for the whole m loop (96 VGPRs)
    bf16x8 qf[Tdim][2];
#pragma unroll
    for (int t = 0; t < Tdim; ++t)
#pragma unroll
        for (int ch = 0; ch < 2; ++ch)
            qf[t][ch] = *(const bf16x8*)&Xb[((size_t)t * 1024 + n0 + l15) * 64 + ch * 32 + q * 8];

    f32x4 oacc[3][4];
#pragma unroll
    for (int j = 0; j < 3; ++j)
#pragma unroll
        for (int ct = 0; ct < 4; ++ct) oacc[j][ct] = (f32x4)0.f;

    // permuted A-row base for score tiles
    const int permA = (l15 >> 2) * 8 + (l15 & 3);

    for (int m0 = 0; m0 < Ndim; m0 += 32) {
        bf16x4 pa[2][3];   // [tau][own-t] packed P fragments
#pragma unroll
        for (int tau = 0; tau < 2; ++tau) {
            int mrow = m0 + permA + 4 * tau;
            f32x4 s[Tdim];
#pragma unroll
            for (int t = 0; t < Tdim; ++t) {
                const short* kb = &Xb[((size_t)t * 1024 + mrow) * 64 + q * 8];
                bf16x8 a0 = *(const bf16x8*)kb;
                bf16x8 a1 = *(const bf16x8*)(kb + 32);
                f32x4 acc = (f32x4)0.f;
                acc = __builtin_amdgcn_mfma_f32_16x16x32_bf16(a0, qf[t][0], acc, 0, 0, 0);
                acc = __builtin_amdgcn_mfma_f32_16x16x32_bf16(a1, qf[t][1], acc, 0, 0, 0);
                s[t] = acc;   // s[t][r] = S_t[m0 + q*8 + r + 4tau][n0 + l15]
            }
            // register softmax over t (4 independent (n,m) slots per lane)
            f32x4 mx = s[0];
#pragma unroll
            for (int t = 1; t < Tdim; ++t)
#pragma unroll
                for (int r = 0; r < 4; ++r) mx[r] = fmaxf(mx[r], s[t][r]);
            f32x4 sum = (f32x4)0.f;
#pragma unroll
            for (int t = 0; t < Tdim; ++t) {
#pragma unroll
                for (int r = 0; r < 4; ++r) s[t][r] = __expf(s[t][r] - mx[r]);
                sum += s[t];
            }
            f32x4 inv;
#pragma unroll
            for (int r = 0; r < 4; ++r) inv[r] = __builtin_amdgcn_rcpf(sum[r]);
            // pack this wave's 3 t's
#pragma unroll
            for (int j = 0; j < 3; ++j) {
                int t = w * 3 + j;
                bf16x4 p4;
#pragma unroll
                for (int r = 0; r < 4; ++r) p4[r] = f2bf(s[t][r] * inv[r]);
                pa[tau][j] = p4;
            }
        }

        // PV: A = [pa0|pa1] (k = q*8 + 0..7), B = contiguous xT bf16x8
#pragma unroll
        for (int j = 0; j < 3; ++j) {
            int t = w * 3 + j;
            bf16x8 pf;
#pragma unroll
            for (int e = 0; e < 4; ++e) { pf[e] = pa[0][j][e]; pf[e + 4] = pa[1][j][e]; }
#pragma unroll
            for (int ct = 0; ct < 4; ++ct) {
                bf16x8 bv = *(const bf16x8*)&XT[((size_t)t * 64 + ct * 16 + l15) * 1024 + m0 + q * 8];
                oacc[j][ct] = __builtin_amdgcn_mfma_f32_16x16x32_bf16(pf, bv, oacc[j][ct], 0, 0, 0);
            }
        }
    }

    float beta = beta_p[0];
#pragma unroll
    for (int j = 0; j < 3; ++j) {
        int t = w * 3 + j;
#pragma unroll
        for (int ct = 0; ct < 4; ++ct) {
#pragma unroll
            for (int r = 0; r < 4; ++r) {
                size_t idx = (((size_t)b * Tdim + t) * Ndim + n0 + q * 4 + r) * Cdim
                           + ct * 16 + l15;
                Out[idx] += beta * fmaxf(oacc[j][ct][r], 0.f);
            }
        }
    }
}

// ---------------------------------------------------------------- bias = S @ bpool (f32)
__global__ __launch_bounds__(256) void k_bias(
    const short* __restrict__ Sbf, const float* __restrict__ bpool,
    float* __restrict__ bias)
{
    int n0 = blockIdx.x * 16;
    int tid = threadIdx.x;
    int o = tid & 63, rg = tid >> 6;
    float acc[4] = {};
    for (int k = 0; k < 1024; ++k) {
        float bp = bpool[(size_t)k * 64 + o];
#pragma unroll
        for (int r = 0; r < 4; ++r)
            acc[r] += bf2f(Sbf[(size_t)(n0 + rg + r * 4) * 1024 + k]) * bp;
    }
#pragma unroll
    for (int r = 0; r < 4; ++r)
        bias[(size_t)(n0 + rg + r * 4) * 64 + o] = acc[r];
}

// ---------------------------------------------------------------- gconv via MFMA (6 waves)
__global__ __launch_bounds__(384) void k_gconv(
    const short* __restrict__ xgT, const short* __restrict__ Wb,
    const float* __restrict__ bias, float* __restrict__ Out,
    const float* __restrict__ alpha_p)
{
    __shared__ short Wl[64 * 64];
    int n = blockIdx.x;
    int tid = threadIdx.x;
    for (int f = tid; f < 512; f += 384) {
        int k = f >> 3, j = f & 7;
        *(bf16x8*)&Wl[k * 64 + (j ^ ((k >> 3) & 7)) * 8] =
            *(const bf16x8*)&Wb[(size_t)n * IOdim + f * 8];
    }
    __syncthreads();
    int w = tid / 64, l = tid & 63, l15 = l & 15, q = l >> 4;
    f32x4 acc[4];
#pragma unroll
    for (int ct = 0; ct < 4; ++ct) acc[ct] = (f32x4)0.f;
    const short* xr = xgT + (size_t)n * Jdim + (size_t)(w * 16 + l15) * 64;
#pragma unroll
    for (int ks = 0; ks < 2; ++ks) {
        bf16x8 a = *(const bf16x8*)&xr[ks * 32 + q * 8];
        int kb = ks * 32 + q * 8;
        int msk = (kb >> 3) & 7;
#pragma unroll
        for (int ct = 0; ct < 4; ++ct) {
            bf16x8 bfr;
#pragma unroll
            for (int e = 0; e < 8; ++e) {
                int o = ct * 16 + l15;
                bfr[e] = Wl[(kb + e) * 64 + (((o >> 3) ^ msk) * 8) + (o & 7)];
            }
            acc[ct] = __builtin_amdgcn_mfma_f32_16x16x32_bf16(a, bfr, acc[ct], 0, 0, 0);
        }
    }
    float alpha = alpha_p[0];
#pragma unroll
    for (int ct = 0; ct < 4; ++ct) {
        int o = ct * 16 + l15;
        float bo = bias[(size_t)n * 64 + o];
#pragma unroll
        for (int r = 0; r < 4; ++r) {
            int bt = w * 16 + q * 4 + r;
            size_t idx = (size_t)bt * 65536 + (size_t)n * 64 + o;
            Out[idx] += alpha * fmaxf(acc[ct][r] + bo, 0.f);
        }
    }
}

// ---------------------------------------------------------------- launch
extern "C" void kernel_launch(void* const* d_in, const int* in_sizes, int n_in,
                              void* d_out, int out_size, void* d_ws, size_t ws_size,
                              hipStream_t stream)
{
    const float* x     = (const float*)d_in[0];
    const float* e1    = (const float*)d_in[1];
    const float* e2    = (const float*)d_in[2];
    const float* Asym  = (const float*)d_in[3];
    const float* wpool = (const float*)d_in[4];
    const float* bpool = (const float*)d_in[5];
    const float* alpha = (const float*)d_in[6];
    const float* beta  = (const float*)d_in[7];
    const float* gamma = (const float*)d_in[8];
    float* out = (float*)d_out;

    short* ASbf = (short*)d_ws;                       // 2048x1024
    short* xbf  = ASbf + 2048 * 1024;
    short* xT   = xbf  + 6291456;
    short* wpT  = xT   + 6291456;
    short* Wbf  = wpT  + 4194304;
    short* xgT  = Wbf  + 4194304;
    float* bias = (float*)(xgT + 6291456);

    k_supports<<<4096, 256, 0, stream>>>(e1, e2, ASbf + 1024 * 1024);
    k_softmax_rows<<<1024, 256, 0, stream>>>(Asym, ASbf);
    k_cvt_x<<<dim3(16, 96), 256, 0, stream>>>(x, xbf, xT);
    k_cvt_wp<<<dim3(64, 16), 256, 0, stream>>>(wpool, wpT);
    // stacked: rows 0..1023 -> out = gamma*relu(A@x); rows 1024..2047 -> xgT = S@x
    k_gemm_bt<0><<<dim3(16, 48), 256, 0, stream>>>(ASbf, xT, out, xgT, gamma);
    // Wbf = S @ wpool
    k_gemm_bt<1><<<dim3(8, 32), 256, 0, stream>>>(ASbf + 1024 * 1024, wpT, nullptr, Wbf, nullptr);
    k_bias<<<64, 256, 0, stream>>>(ASbf + 1024 * 1024, bpool, bias);
    // out += beta * relu(x_sa)
    k_sa4<<<dim3(Bdim, Ndim / 16), 256, 0, stream>>>(xbf, xT, out, beta);
    // out += alpha * relu(xgT @ W[n] + bias[n])
    k_gconv<<<1024, 384, 0, stream>>>(xgT, Wbf, bias, out, alpha);
}